// Round 1
// baseline (121.649 us; speedup 1.0000x reference)
//
#include <hip/hip_runtime.h>

#define NTYPES 64
#define DIM 64          // IN_DIM == OUT_DIM == 64
#define LXS 68          // padded LDS row stride (floats): 68*4=272B, 16B-aligned, bank-safe

// ---------------- K1: histogram of types ----------------
__global__ void hist_k(const int* __restrict__ types, int n, int* __restrict__ counts) {
    __shared__ int lh[NTYPES];
    int tid = threadIdx.x;
    if (tid < NTYPES) lh[tid] = 0;
    __syncthreads();
    for (int i = blockIdx.x * blockDim.x + tid; i < n; i += gridDim.x * blockDim.x)
        atomicAdd(&lh[types[i]], 1);
    __syncthreads();
    if (tid < NTYPES) {
        int c = lh[tid];
        if (c) atomicAdd(&counts[tid], c);
    }
}

// ---------------- K2: exclusive scan (64 elements, trivial) ----------------
__global__ void scan_k(const int* __restrict__ counts, int* __restrict__ start,
                       int* __restrict__ cursor) {
    if (threadIdx.x == 0) {
        int acc = 0;
        for (int t = 0; t < NTYPES; ++t) {
            start[t] = acc;
            cursor[t] = acc;
            acc += counts[t];
        }
        start[NTYPES] = acc;
    }
}

// ---------------- K3: block-aggregated scatter -> perm sorted by type ----------------
__global__ void scatter_k(const int* __restrict__ types, int n, int* __restrict__ cursor,
                          int* __restrict__ perm) {
    __shared__ int lh[NTYPES];
    __shared__ int lbase[NTYPES];
    int tid = threadIdx.x;
    if (tid < NTYPES) lh[tid] = 0;
    __syncthreads();
    const int PER = 4;
    int base = blockIdx.x * blockDim.x * PER;
    int myt[PER], myo[PER];
    #pragma unroll
    for (int k = 0; k < PER; ++k) {
        int i = base + k * blockDim.x + tid;   // coalesced
        if (i < n) {
            int t = types[i];
            myt[k] = t;
            myo[k] = atomicAdd(&lh[t], 1);
        } else {
            myt[k] = -1;
        }
    }
    __syncthreads();
    if (tid < NTYPES) lbase[tid] = lh[tid] ? atomicAdd(&cursor[tid], lh[tid]) : 0;
    __syncthreads();
    #pragma unroll
    for (int k = 0; k < PER; ++k)
        if (myt[k] >= 0)
            perm[lbase[myt[k]] + myo[k]] = base + k * blockDim.x + tid;
}

// ---------------- K4: grouped GEMV main kernel ----------------
// grid = (64 types, NBY batch-slots); block = 256 = 4 waves.
// Per 64-atom batch: stage x rows coalesced into padded LDS; wave w computes
// output columns [16w,16w+16) for all 64 atoms (lane = atom). Matrix values are
// wave-uniform -> s_load -> SGPR operand of v_fmac_f32.
__global__ __launch_bounds__(256) void main_k(const float* __restrict__ x,
                                              const float* __restrict__ M,
                                              const float* __restrict__ bias,
                                              const int* __restrict__ start,
                                              const int* __restrict__ perm,
                                              float* __restrict__ out) {
    int t = blockIdx.x;                 // type (uniform)
    int s0 = start[t];
    int cnt = start[t + 1] - s0;
    int tid = threadIdx.x;
    int lane = tid & 63;
    // force wave id into an SGPR so M/bias addresses are provably uniform
    int wave = __builtin_amdgcn_readfirstlane(tid >> 6);
    int o0 = wave * 16;

    const float* Mt = M + ((size_t)t << 12);      // t*64*64
    const float* Bt = bias + t * DIM + o0;

    float bv[16];
    #pragma unroll
    for (int k = 0; k < 16; ++k) bv[k] = Bt[k];   // uniform -> SGPR

    __shared__ __align__(16) float lx[64 * LXS];  // 17.4 KB

    for (int bb = blockIdx.y; bb * 64 < cnt; bb += gridDim.y) {
        int abase = s0 + bb * 64;
        int nA = cnt - bb * 64; if (nA > 64) nA = 64;

        // ---- stage x: 4 threads per row, 16 floats each, coalesced ----
        {
            int row = tid >> 2;
            int q   = tid & 3;
            if (row < nA) {
                int a = perm[abase + row];
                const float4* src = (const float4*)(x + (size_t)a * DIM + 16 * q);
                float4* dst = (float4*)(lx + row * LXS + 16 * q);
                dst[0] = src[0]; dst[1] = src[1]; dst[2] = src[2]; dst[3] = src[3];
            }
        }
        __syncthreads();

        // ---- compute: lane = atom, this wave covers outputs [o0, o0+16) ----
        float acc[16];
        #pragma unroll
        for (int k = 0; k < 16; ++k) acc[k] = bv[k];

        const float4* xr = (const float4*)(lx + lane * LXS);
        const float* Mw = Mt + o0;
        #pragma unroll
        for (int i4 = 0; i4 < 16; ++i4) {
            float4 xv = xr[i4];
            {
                const float* m = Mw + (i4 * 4 + 0) * DIM;
                #pragma unroll
                for (int k = 0; k < 16; ++k) acc[k] = fmaf(xv.x, m[k], acc[k]);
            }
            {
                const float* m = Mw + (i4 * 4 + 1) * DIM;
                #pragma unroll
                for (int k = 0; k < 16; ++k) acc[k] = fmaf(xv.y, m[k], acc[k]);
            }
            {
                const float* m = Mw + (i4 * 4 + 2) * DIM;
                #pragma unroll
                for (int k = 0; k < 16; ++k) acc[k] = fmaf(xv.z, m[k], acc[k]);
            }
            {
                const float* m = Mw + (i4 * 4 + 3) * DIM;
                #pragma unroll
                for (int k = 0; k < 16; ++k) acc[k] = fmaf(xv.w, m[k], acc[k]);
            }
        }

        // ---- store: per-lane row, 64B segment [o0, o0+16) of out row ----
        if (lane < nA) {
            int a = perm[abase + lane];
            float4* o4 = (float4*)(out + (size_t)a * DIM + o0);
            o4[0] = make_float4(acc[0],  acc[1],  acc[2],  acc[3]);
            o4[1] = make_float4(acc[4],  acc[5],  acc[6],  acc[7]);
            o4[2] = make_float4(acc[8],  acc[9],  acc[10], acc[11]);
            o4[3] = make_float4(acc[12], acc[13], acc[14], acc[15]);
        }
        __syncthreads();   // protect lx before next batch's staging
    }
}

extern "C" void kernel_launch(void* const* d_in, const int* in_sizes, int n_in,
                              void* d_out, int out_size, void* d_ws, size_t ws_size,
                              hipStream_t stream) {
    const float* x     = (const float*)d_in[0];
    const int*   types = (const int*)d_in[1];
    const float* M     = (const float*)d_in[2];
    const float* bias  = (const float*)d_in[3];
    float* out = (float*)d_out;
    int n = in_sizes[1];              // number of atoms

    // ws layout (ints): counts[64] | start[65] | cursor[64] | pad | perm[n]
    int* counts = (int*)d_ws;
    int* start  = counts + 64;
    int* cursor = counts + 129;
    int* perm   = counts + 256;

    hipMemsetAsync(counts, 0, 64 * sizeof(int), stream);

    hist_k<<<128, 256, 0, stream>>>(types, n, counts);
    scan_k<<<1, 64, 0, stream>>>(counts, start, cursor);
    scatter_k<<<(n + 1023) / 1024, 256, 0, stream>>>(types, n, cursor, perm);
    main_k<<<dim3(NTYPES, 26), 256, 0, stream>>>(x, M, bias, start, perm, out);
}

// Round 2
// 121.270 us; speedup vs baseline: 1.0031x; 1.0031x over previous
//
#include <hip/hip_runtime.h>

#define NTYPES 64
#define DIM 64
#define HBLOCKS 128       // histogram blocks
#define CHUNK 128         // atoms per block-batch in main_k
#define XSTR 132          // xT row stride (floats): 132*4=528B, 16B-aligned, +4-bank skew

// ---------------- K1: histogram -> per-block partial counts (no atomics to global) ----
__global__ void hist_k(const int* __restrict__ types, int n, int* __restrict__ part) {
    __shared__ int lh[NTYPES];
    int tid = threadIdx.x;
    if (tid < NTYPES) lh[tid] = 0;
    __syncthreads();
    for (int i = blockIdx.x * blockDim.x + tid; i < n; i += gridDim.x * blockDim.x)
        atomicAdd(&lh[types[i]], 1);
    __syncthreads();
    if (tid < NTYPES) part[blockIdx.x * NTYPES + tid] = lh[tid];
}

// ---------------- K2: reduce partials + wave-parallel exclusive scan ----------------
__global__ void scan_k(const int* __restrict__ part, int* __restrict__ start,
                       int* __restrict__ cursor) {
    int t = threadIdx.x;               // 64 threads = 1 wave
    int sum = 0;
    for (int b = 0; b < HBLOCKS; ++b)  // coalesced 256B rows
        sum += part[b * NTYPES + t];
    int inc = sum;
    #pragma unroll
    for (int d = 1; d < 64; d <<= 1) {
        int u = __shfl_up(inc, d);
        if (t >= d) inc += u;
    }
    int exc = inc - sum;
    start[t] = exc;
    cursor[t] = exc;
    if (t == 63) start[NTYPES] = inc;
}

// ---------------- K3: block-aggregated scatter -> perm sorted by type ----------------
__global__ void scatter_k(const int* __restrict__ types, int n, int* __restrict__ cursor,
                          int* __restrict__ perm) {
    __shared__ int lh[NTYPES];
    __shared__ int lbase[NTYPES];
    int tid = threadIdx.x;
    if (tid < NTYPES) lh[tid] = 0;
    __syncthreads();
    const int PER = 4;
    int base = blockIdx.x * blockDim.x * PER;
    int myt[PER], myo[PER];
    #pragma unroll
    for (int k = 0; k < PER; ++k) {
        int i = base + k * blockDim.x + tid;
        if (i < n) {
            int t = types[i];
            myt[k] = t;
            myo[k] = atomicAdd(&lh[t], 1);
        } else {
            myt[k] = -1;
        }
    }
    __syncthreads();
    if (tid < NTYPES) lbase[tid] = lh[tid] ? atomicAdd(&cursor[tid], lh[tid]) : 0;
    __syncthreads();
    #pragma unroll
    for (int k = 0; k < PER; ++k)
        if (myt[k] >= 0)
            perm[lbase[myt[k]] + myo[k]] = base + k * blockDim.x + tid;
}

// ---------------- K4: grouped GEMM, register-blocked from LDS ----------------
// grid = (64 types, 14 chunk-slots); block = 128 threads (2 waves).
// Per block: stage M[64][64] (16KB) once; per 128-atom batch stage x transposed
// (xT[k][atom], 33.8KB); thread (r=tid>>3, c=tid&7) computes 8 atoms x 8 outs.
// Per k: 2 ds_read_b128 (x) + 2 ds_read_b128 (M, 8-way broadcast) + 64 v_fmac.
__global__ __launch_bounds__(128) void main_k(const float* __restrict__ x,
                                              const float* __restrict__ M,
                                              const float* __restrict__ bias,
                                              const int* __restrict__ start,
                                              const int* __restrict__ perm,
                                              float* __restrict__ out) {
    int t = blockIdx.x;
    int s0 = start[t];
    int cnt = start[t + 1] - s0;
    int tid = threadIdx.x;

    __shared__ __align__(16) float Ms[DIM * DIM];      // 16 KB, linear row-major
    __shared__ __align__(16) float xT[DIM * XSTR];     // 33.8 KB, xT[k][atom]

    // stage M coalesced: 1024 float4 / 128 threads = 8 each
    {
        const float4* src = (const float4*)(M + ((size_t)t << 12));
        float4* dst = (float4*)Ms;
        #pragma unroll
        for (int i = 0; i < 8; ++i) dst[tid + 128 * i] = src[tid + 128 * i];
    }

    int c = tid & 7;          // output group
    int r = tid >> 3;         // atom group (16 groups x 8 atoms)
    int o0 = c * 8;
    int a0 = r * 8;

    float bv[8];
    {
        float4 b1 = *(const float4*)(bias + t * DIM + o0);
        float4 b2 = *(const float4*)(bias + t * DIM + o0 + 4);
        bv[0]=b1.x; bv[1]=b1.y; bv[2]=b1.z; bv[3]=b1.w;
        bv[4]=b2.x; bv[5]=b2.y; bv[6]=b2.z; bv[7]=b2.w;
    }

    int srow = tid >> 4;      // 0..7  (8 rows per pass)
    int sseg = tid & 15;      // 0..15 (16B segment within row)

    for (int bb = blockIdx.y; bb * CHUNK < cnt; bb += gridDim.y) {
        int abase = s0 + bb * CHUNK;
        int nA = cnt - bb * CHUNK; if (nA > CHUNK) nA = CHUNK;

        __syncthreads();   // M staged (iter 0) / xT from prev batch consumed

        // ---- stage x transposed: 16 passes x 8 rows, coalesced 16B gathers ----
        #pragma unroll 4
        for (int p = 0; p < 16; ++p) {
            int row = srow + p * 8;
            if (row < nA) {
                int g = perm[abase + row];
                float4 v = *(const float4*)(x + ((size_t)g << 6) + sseg * 4);
                xT[(4 * sseg + 0) * XSTR + row] = v.x;
                xT[(4 * sseg + 1) * XSTR + row] = v.y;
                xT[(4 * sseg + 2) * XSTR + row] = v.z;
                xT[(4 * sseg + 3) * XSTR + row] = v.w;
            }
        }
        __syncthreads();

        // ---- compute 8x8 tile ----
        float acc[8][8];
        #pragma unroll
        for (int j = 0; j < 8; ++j)
            #pragma unroll
            for (int k = 0; k < 8; ++k) acc[j][k] = bv[k];

        #pragma unroll 4
        for (int k = 0; k < DIM; ++k) {
            float4 xa = *(const float4*)(xT + k * XSTR + a0);
            float4 xb = *(const float4*)(xT + k * XSTR + a0 + 4);
            float4 ma = *(const float4*)(Ms + k * DIM + o0);
            float4 mb = *(const float4*)(Ms + k * DIM + o0 + 4);
            float xv[8] = {xa.x, xa.y, xa.z, xa.w, xb.x, xb.y, xb.z, xb.w};
            float mv[8] = {ma.x, ma.y, ma.z, ma.w, mb.x, mb.y, mb.z, mb.w};
            #pragma unroll
            for (int j = 0; j < 8; ++j)
                #pragma unroll
                for (int q = 0; q < 8; ++q)
                    acc[j][q] = fmaf(xv[j], mv[q], acc[j][q]);
        }

        // ---- store: out[perm[a]][o0:o0+8], guarded per atom ----
        #pragma unroll
        for (int j = 0; j < 8; ++j) {
            int a = a0 + j;
            if (a < nA) {
                int g = perm[abase + a];
                float4* o4 = (float4*)(out + ((size_t)g << 6) + o0);
                o4[0] = make_float4(acc[j][0], acc[j][1], acc[j][2], acc[j][3]);
                o4[1] = make_float4(acc[j][4], acc[j][5], acc[j][6], acc[j][7]);
            }
        }
    }
}

extern "C" void kernel_launch(void* const* d_in, const int* in_sizes, int n_in,
                              void* d_out, int out_size, void* d_ws, size_t ws_size,
                              hipStream_t stream) {
    const float* x     = (const float*)d_in[0];
    const int*   types = (const int*)d_in[1];
    const float* M     = (const float*)d_in[2];
    const float* bias  = (const float*)d_in[3];
    float* out = (float*)d_out;
    int n = in_sizes[1];

    // ws layout (ints): part[128*64] | start[65] | cursor[64] | pad | perm[n]
    int* part   = (int*)d_ws;
    int* start  = part + HBLOCKS * NTYPES;
    int* cursor = start + 65;
    int* perm   = part + HBLOCKS * NTYPES + 256;

    hist_k<<<HBLOCKS, 256, 0, stream>>>(types, n, part);
    scan_k<<<1, 64, 0, stream>>>(part, start, cursor);
    scatter_k<<<(n + 1023) / 1024, 256, 0, stream>>>(types, n, cursor, perm);
    main_k<<<dim3(NTYPES, 14), 128, 0, stream>>>(x, M, bias, start, perm, out);
}

// Round 3
// 95.298 us; speedup vs baseline: 1.2765x; 1.2725x over previous
//
#include <hip/hip_runtime.h>
#include <hip/hip_bf16.h>

#define NTYPES 64
#define DIM 64
#define HB 64            // histogram blocks
#define MT_STR 72        // Mt row stride in bf16 elems: 144B, 16B-aligned

typedef short bf16x8 __attribute__((ext_vector_type(8)));
typedef float f32x4  __attribute__((ext_vector_type(4)));

static __device__ __forceinline__ short f2bf(float f) {
    __hip_bfloat16 h = __float2bfloat16(f);   // RNE
    return *reinterpret_cast<short*>(&h);
}

// ---------------- K1: per-block partial histograms (no global atomics, no memset) ----
__global__ void hist_k(const int* __restrict__ types, int n, int* __restrict__ part) {
    __shared__ int lh[NTYPES];
    int tid = threadIdx.x;
    if (tid < NTYPES) lh[tid] = 0;
    __syncthreads();
    for (int i = blockIdx.x * blockDim.x + tid; i < n; i += gridDim.x * blockDim.x)
        atomicAdd(&lh[types[i]], 1);
    __syncthreads();
    if (tid < NTYPES) part[blockIdx.x * NTYPES + tid] = lh[tid];
}

// ---------------- K2: parallel reduce of partials + wave shfl-scan ----------------
__global__ void scan_k(const int* __restrict__ part, int* __restrict__ start,
                       int* __restrict__ cursor) {
    __shared__ int ps[4][NTYPES];
    int tid = threadIdx.x;
    int t = tid & 63, seg = tid >> 6;          // 256 threads: 4 segs x 16 blocks
    int s = 0;
    #pragma unroll
    for (int i = 0; i < HB / 4; ++i)
        s += part[(seg * (HB / 4) + i) * NTYPES + t];
    ps[seg][t] = s;
    __syncthreads();
    if (tid < 64) {
        int sum = ps[0][t] + ps[1][t] + ps[2][t] + ps[3][t];
        int inc = sum;
        #pragma unroll
        for (int d = 1; d < 64; d <<= 1) {
            int u = __shfl_up(inc, d);
            if (t >= d) inc += u;
        }
        int exc = inc - sum;
        start[t] = exc;
        cursor[t] = exc;
        if (t == 63) start[NTYPES] = inc;
    }
}

// ---------------- K3: block-aggregated scatter -> perm sorted by type ----------------
__global__ void scatter_k(const int* __restrict__ types, int n, int* __restrict__ cursor,
                          int* __restrict__ perm) {
    __shared__ int lh[NTYPES];
    __shared__ int lbase[NTYPES];
    int tid = threadIdx.x;
    if (tid < NTYPES) lh[tid] = 0;
    __syncthreads();
    const int PER = 4;
    int base = blockIdx.x * blockDim.x * PER;
    int myt[PER], myo[PER];
    #pragma unroll
    for (int k = 0; k < PER; ++k) {
        int i = base + k * blockDim.x + tid;
        if (i < n) {
            int t = types[i];
            myt[k] = t;
            myo[k] = atomicAdd(&lh[t], 1);
        } else {
            myt[k] = -1;
        }
    }
    __syncthreads();
    if (tid < NTYPES) lbase[tid] = lh[tid] ? atomicAdd(&cursor[tid], lh[tid]) : 0;
    __syncthreads();
    #pragma unroll
    for (int k = 0; k < PER; ++k)
        if (myt[k] >= 0)
            perm[lbase[myt[k]] + myo[k]] = base + k * blockDim.x + tid;
}

// ---------------- K4: MFMA grouped GEMM ----------------
// grid = (64 types, 26 slots), block = 256 (4 waves).
// Per (type, 64-atom chunk): wave w computes atoms [16w,16w+16) x all 64 outs.
// A (x) bf16 from global per-lane; B = bf16(M^T) staged once per block in LDS.
// mfma_f32_16x16x32_bf16: A lane l -> row=l&15, k=(l>>4)*8+j ; B lane l ->
// k=(l>>4)*8+j, col=l&15 ; D lane l -> row=(l>>4)*4+r, col=l&15 (m89-verified).
__global__ __launch_bounds__(256) void main_k(const float* __restrict__ x,
                                              const float* __restrict__ M,
                                              const float* __restrict__ bias,
                                              const int* __restrict__ start,
                                              const int* __restrict__ perm,
                                              float* __restrict__ out) {
    int t = blockIdx.x;
    int s0 = start[t];
    int cnt = start[t + 1] - s0;
    if ((int)blockIdx.y * 64 >= cnt) return;   // empty slot

    int tid = threadIdx.x;
    int lane = tid & 63;
    int wave = tid >> 6;       // 0..3 = atom stripe
    int col  = lane & 15;
    int hi   = lane >> 4;      // 0..3

    __shared__ __align__(16) short Mt[DIM * MT_STR];   // Mt[o][k] bf16, 9216B

    // ---- stage Mt = bf16(M[t]^T), coalesced float4 reads ----
    {
        const float4* Msrc = (const float4*)(M + ((size_t)t << 12));
        #pragma unroll
        for (int i = 0; i < 4; ++i) {
            int f  = tid + 256 * i;       // 0..1023
            int k  = f >> 4;              // row of M = k index
            int o4 = (f & 15) * 4;        // 4 consecutive outs
            float4 v = Msrc[f];
            Mt[(o4 + 0) * MT_STR + k] = f2bf(v.x);
            Mt[(o4 + 1) * MT_STR + k] = f2bf(v.y);
            Mt[(o4 + 2) * MT_STR + k] = f2bf(v.z);
            Mt[(o4 + 3) * MT_STR + k] = f2bf(v.w);
        }
    }

    float bcol[4];
    #pragma unroll
    for (int ct = 0; ct < 4; ++ct) bcol[ct] = bias[t * DIM + ct * 16 + col];

    __syncthreads();           // Mt ready; read-only afterwards -> no barriers in loop

    int lim = s0 + cnt;
    for (int bb = blockIdx.y; bb * 64 < cnt; bb += gridDim.y) {
        int abase = s0 + bb * 64;
        int nA = cnt - bb * 64; if (nA > 64) nA = 64;

        // ---- A fragments: this lane's atom row = wave*16 + col ----
        int aidx = abase + wave * 16 + col;
        if (aidx >= lim) aidx = s0;                 // clamp: read a real row, guard at store
        int g = perm[aidx];
        const float* xr = x + ((size_t)g << 6);
        float4 p0 = *(const float4*)(xr + hi * 8);
        float4 p1 = *(const float4*)(xr + hi * 8 + 4);
        float4 p2 = *(const float4*)(xr + 32 + hi * 8);
        float4 p3 = *(const float4*)(xr + 32 + hi * 8 + 4);
        bf16x8 af0, af1;
        af0[0] = f2bf(p0.x); af0[1] = f2bf(p0.y); af0[2] = f2bf(p0.z); af0[3] = f2bf(p0.w);
        af0[4] = f2bf(p1.x); af0[5] = f2bf(p1.y); af0[6] = f2bf(p1.z); af0[7] = f2bf(p1.w);
        af1[0] = f2bf(p2.x); af1[1] = f2bf(p2.y); af1[2] = f2bf(p2.z); af1[3] = f2bf(p2.w);
        af1[4] = f2bf(p3.x); af1[5] = f2bf(p3.y); af1[6] = f2bf(p3.z); af1[7] = f2bf(p3.w);

        // ---- 4 col-tiles x 2 K-halves of MFMA, acc initialized with bias ----
        f32x4 acc[4];
        #pragma unroll
        for (int ct = 0; ct < 4; ++ct) {
            acc[ct][0] = bcol[ct]; acc[ct][1] = bcol[ct];
            acc[ct][2] = bcol[ct]; acc[ct][3] = bcol[ct];
        }
        #pragma unroll
        for (int ct = 0; ct < 4; ++ct) {
            const short* mrow = Mt + (ct * 16 + col) * MT_STR;
            bf16x8 b0 = *(const bf16x8*)(mrow + hi * 8);        // k in [0,32)
            bf16x8 b1 = *(const bf16x8*)(mrow + 32 + hi * 8);   // k in [32,64)
            acc[ct] = __builtin_amdgcn_mfma_f32_16x16x32_bf16(af0, b0, acc[ct], 0, 0, 0);
            acc[ct] = __builtin_amdgcn_mfma_f32_16x16x32_bf16(af1, b1, acc[ct], 0, 0, 0);
        }

        // ---- store: lane holds D[row=hi*4+r][col] per tile ----
        #pragma unroll
        for (int r = 0; r < 4; ++r) {
            int arow = wave * 16 + hi * 4 + r;
            if (arow < nA) {
                int g2 = perm[abase + arow];
                float* orow = out + ((size_t)g2 << 6) + col;
                #pragma unroll
                for (int ct = 0; ct < 4; ++ct)
                    orow[ct * 16] = acc[ct][r];
            }
        }
    }
}

extern "C" void kernel_launch(void* const* d_in, const int* in_sizes, int n_in,
                              void* d_out, int out_size, void* d_ws, size_t ws_size,
                              hipStream_t stream) {
    const float* x     = (const float*)d_in[0];
    const int*   types = (const int*)d_in[1];
    const float* M     = (const float*)d_in[2];
    const float* bias  = (const float*)d_in[3];
    float* out = (float*)d_out;
    int n = in_sizes[1];

    // ws (ints): part[64*64] | start[65] | cursor[64] | pad | perm[n]
    int* part   = (int*)d_ws;
    int* start  = part + HB * NTYPES;
    int* cursor = start + 65;
    int* perm   = part + HB * NTYPES + 256;

    hist_k<<<HB, 256, 0, stream>>>(types, n, part);
    scan_k<<<1, 256, 0, stream>>>(part, start, cursor);
    scatter_k<<<(n + 1023) / 1024, 256, 0, stream>>>(types, n, cursor, perm);
    main_k<<<dim3(NTYPES, 26), 256, 0, stream>>>(x, M, bias, start, perm, out);
}